// Round 8
// baseline (340.885 us; speedup 1.0000x reference)
//
#include <hip/hip_runtime.h>

// out[b] = M[b] @ X[b] + bias2, where (X = x_in[b] as [192,16384])
//   G[b]  = X X^T (Gram) ; Wq'=w_q@w_split etc.; Wo2=w_out@w_proj; bias2=w_out@b_proj
//   U = [Wk';Wq'] G ; Tk = U[0:192] ; kn[d]=sqrt(U_k[d]·Wk'[d]) ; qn[d]=sqrt(U_q[d]·Wq'[d])
//   S = Tk Wq'^T ; A = softmax_rows(S/(kn⊗qn)) ; Tv = A Wv' ; M = Wo2 Tv
// All GEMM phases: bf16 MFMA 16x16x32, fp32 accum. middle8 fuses tkqn2+attn2+m2
// into ONE kernel: 8 blocks (1/batch) x 384 thr, two 76.8 KB LDS regions
// time-shared across 5 GEMM phases; Tk/A/Tvt never touch global.
// LDS budget: 2*76800 + 1536 = 155136 B < 163840 B (gfx950 per-WG max); round 6
// already ran 102 KB static LDS on this harness. Round-7 bench was an infra
// failure (container failed twice, no pytest/absmax signal) -> resubmit.

static constexpr int B_ = 8;
static constexpr int C_ = 192;
static constexpr int N_ = 16384;
static constexpr int CC2 = C_ * C_;
static constexpr int NCHUNK = 32;

using u16x8 = __attribute__((ext_vector_type(8))) unsigned short;
using bf16x8 = __attribute__((ext_vector_type(8))) __bf16;
using f32x4 = __attribute__((ext_vector_type(4))) float;
using uint32x4 = __attribute__((ext_vector_type(4))) unsigned int;

__device__ __forceinline__ unsigned short f2bf(float f) {
  unsigned int u = __builtin_bit_cast(unsigned int, f);
  u += 0x7FFFu + ((u >> 16) & 1u);   // RNE
  return (unsigned short)(u >> 16);
}

// packed f32x2 -> bf16x2 (compiler emits v_cvt_pk_bf16_f32; RNE)
__device__ __forceinline__ unsigned int pkbf(float lo, float hi) {
  unsigned short a = __builtin_bit_cast(unsigned short, (__bf16)lo);
  unsigned short b = __builtin_bit_cast(unsigned short, (__bf16)hi);
  return (unsigned int)a | ((unsigned int)b << 16);
}

// 8 consecutive fp32 (16B-aligned) -> bf16 fragment
__device__ __forceinline__ u16x8 ld8bf(const float* p) {
  float4 u0 = *(const float4*)p;
  float4 u1 = *(const float4*)(p + 4);
  uint32x4 w;
  w[0] = pkbf(u0.x, u0.y); w[1] = pkbf(u0.z, u0.w);
  w[2] = pkbf(u1.x, u1.y); w[3] = pkbf(u1.z, u1.w);
  return __builtin_bit_cast(u16x8, w);
}

__device__ __forceinline__ float f4get(const float4& v, int e) {
  return (e == 0) ? v.x : (e == 1) ? v.y : (e == 2) ? v.z : v.w;
}

__device__ __forceinline__ f32x4 mfma16(u16x8 a, u16x8 b, f32x4 c) {
  return __builtin_amdgcn_mfma_f32_16x16x32_bf16(
      __builtin_bit_cast(bf16x8, a), __builtin_bit_cast(bf16x8, b), c, 0, 0, 0);
}

// ---------------- fold weights ----------------
__global__ void fold_kernel(const float* __restrict__ wsplit, const float* __restrict__ wq,
                            const float* __restrict__ wk, const float* __restrict__ wv,
                            const float* __restrict__ wproj, const float* __restrict__ bproj,
                            const float* __restrict__ wout,
                            float* __restrict__ Wq, float* __restrict__ WvT,
                            float* __restrict__ Wk, float* __restrict__ Wv,
                            float* __restrict__ Wo2, float* __restrict__ bias2) {
  int idx = blockIdx.x * 256 + threadIdx.x;
  if (idx < C_) {
    float s = 0.f;
    for (int c = 0; c < C_; ++c) s += wout[idx * C_ + c] * bproj[c];
    bias2[idx] = s;
  }
  if (idx >= 4 * CC2) return;
  int which = idx / CC2;
  int rem = idx % CC2;
  int o = rem / C_, c = rem % C_;
  const float* A = (which == 0) ? wq : (which == 1) ? wk : (which == 2) ? wv : wout;
  const float* Bm = (which == 3) ? wproj : wsplit;
  float s = 0.f;
  for (int e = 0; e < C_; ++e) s += A[o * C_ + e] * Bm[e * C_ + c];
  if (which == 0) Wq[rem] = s;
  else if (which == 1) Wk[rem] = s;
  else if (which == 2) { Wv[rem] = s; WvT[c * C_ + o] = s; }
  else Wo2[rem] = s;
}

// ---------------- Gram: row-split x2, double-buffered pipeline (round-2 measured) ----
template <bool ATOMIC>
__global__ __launch_bounds__(384) void gram3_kernel(const float* __restrict__ xin,
                                                    float* __restrict__ dst) {
  const int b = blockIdx.z, half = blockIdx.y, ch = blockIdx.x;
  const int k0 = ch * 512;
  __shared__ unsigned short Xs[2][C_][72];         // dbuf, pitch 72 (2-way = free)
  const int tid = threadIdx.x;
  const int wv = tid >> 6;                         // 0..5
  const int lane = tid & 63;
  const int ln = lane & 15, mq = lane >> 4;
  const int arow0 = half * 96 + wv * 16;           // this wave's 16 G-rows
  const int cbase = tid >> 4;                      // 0..23
  const int k4 = tid & 15;
  const float* xb = xin + (size_t)b * C_ * N_;

  f32x4 acc[12];
#pragma unroll
  for (int j = 0; j < 12; ++j) acc[j] = (f32x4)0.0f;

  float4 ld[8];
  auto load_stage = [&](int kbase) {
#pragma unroll
    for (int j = 0; j < 8; ++j)
      ld[j] = *(const float4*)(xb + (size_t)(j * 24 + cbase) * N_ + kbase + k4 * 4);
  };
  auto write_stage = [&](int buf) {
#pragma unroll
    for (int j = 0; j < 8; ++j) {
      uint2 pk;
      pk.x = pkbf(ld[j].x, ld[j].y);
      pk.y = pkbf(ld[j].z, ld[j].w);
      *(uint2*)&Xs[buf][j * 24 + cbase][k4 * 4] = pk;    // ds_write_b64
    }
  };

  load_stage(k0);
  write_stage(0);
  __syncthreads();
  for (int s = 0; s < 8; ++s) {                    // 8 stages of 64 k
    if (s < 7) load_stage(k0 + (s + 1) * 64);      // prefetch overlaps MFMA
    const int cb = s & 1;
#pragma unroll
    for (int ks = 0; ks < 2; ++ks) {
      const int kk = ks * 32 + mq * 8;
      u16x8 a0 = *(const u16x8*)&Xs[cb][arow0 + ln][kk];
#pragma unroll
      for (int ct = 0; ct < 12; ++ct) {
        u16x8 bf = *(const u16x8*)&Xs[cb][ct * 16 + ln][kk];
        acc[ct] = mfma16(a0, bf, acc[ct]);
      }
    }
    if (s < 7) {
      write_stage(cb ^ 1);   // safe: cb^1 last read a full barrier ago
      __syncthreads();
    }
  }
  float* out = ATOMIC ? dst + (size_t)b * CC2
                      : dst + ((size_t)b * NCHUNK + ch) * CC2;
#pragma unroll
  for (int ct = 0; ct < 12; ++ct)
#pragma unroll
    for (int r = 0; r < 4; ++r) {
      int row = arow0 + mq * 4 + r;
      int col = ct * 16 + ln;
      if (ATOMIC) atomicAdd(&out[row * C_ + col], acc[ct][r]);
      else out[row * C_ + col] = acc[ct][r];
    }
}

// reduce 32 partials -> G. float4. grid (CC2/1024, 8), 256 thr.
__global__ void gsum_kernel(const float* __restrict__ P, float* __restrict__ G) {
  const int j = (blockIdx.x * 256 + threadIdx.x) * 4;
  const int b = blockIdx.y;
  const float* base = P + (size_t)b * NCHUNK * CC2 + j;
  float4 s = {0.f, 0.f, 0.f, 0.f};
#pragma unroll
  for (int ch = 0; ch < NCHUNK; ++ch) {
    float4 v = *(const float4*)(base + (size_t)ch * CC2);
    s.x += v.x; s.y += v.y; s.z += v.z; s.w += v.w;
  }
  *(float4*)(G + (size_t)b * CC2 + j) = s;
}

// ---------------- middle8: tkqn2+attn2+m2 fused, one block per batch ----------------
// 384 thr = 6 waves; each wave owns 32 rows (2 MFMA tile-rows) of every 192-row GEMM.
// LDS: R1 (76.8 KB) = G -> Wq -> WvT -> Tvt^T ; R2 (76.8 KB) = Tk -> A. Pitch 200 u16
// keeps b128 reads & b64 writes 2-way max. kn/qn in 1.5 KB LDS. Phases:
//  0: stage G          1: Tk=Wk·G (+kn), qn pass       2: S=Tk·Wq^T + softmax -> A
//  3: Tv=A·WvT         4: M=Wo2·Tv -> global
__global__ __launch_bounds__(384, 1) void middle8_kernel(
    const float* __restrict__ G, const float* __restrict__ Wk,
    const float* __restrict__ Wq, const float* __restrict__ WvT,
    const float* __restrict__ Wo2, float* __restrict__ Mw) {
  __shared__ __align__(16) unsigned short R1[192 * 200];
  __shared__ __align__(16) unsigned short R2[192 * 200];
  __shared__ float knl[C_], qnl[C_];
  const int b = blockIdx.x;
  const int tid = threadIdx.x;
  const int w = tid >> 6, lane = tid & 63;
  const int ln = lane & 15, mq = lane >> 4;
  const int r0 = w * 32;                           // wave's 32 rows

  auto stage = [&](const float* src, unsigned short* lds) {
#pragma unroll
    for (int i = 0; i < 24; ++i) {                 // 9216 float4 / 384 thr
      int idx = i * 384 + tid;
      int row = idx / 48, c4 = idx % 48;
      float4 v = *(const float4*)(src + (size_t)row * C_ + c4 * 4);
      uint2 pk; pk.x = pkbf(v.x, v.y); pk.y = pkbf(v.z, v.w);
      *(uint2*)&lds[row * 200 + c4 * 4] = pk;
    }
  };

  stage(G + (size_t)b * CC2, R1);
  __syncthreads();

  // ---- phase 1: pass0 Tk=Wk·G -> R2 + kn ; pass1 qn only ----
  for (int pass = 0; pass < 2; ++pass) {
    const float* W2 = pass ? Wq : Wk;
    u16x8 afr[2][6];
#pragma unroll
    for (int i = 0; i < 2; ++i)
#pragma unroll
      for (int kc = 0; kc < 6; ++kc)
        afr[i][kc] = ld8bf(W2 + (size_t)(r0 + i * 16 + ln) * C_ + kc * 32 + mq * 8);
    f32x4 acc[2][12];
#pragma unroll
    for (int i = 0; i < 2; ++i)
#pragma unroll
      for (int j = 0; j < 12; ++j) acc[i][j] = (f32x4)0.0f;
#pragma unroll
    for (int kc = 0; kc < 6; ++kc)
#pragma unroll
      for (int ct = 0; ct < 12; ++ct) {
        u16x8 g = *(const u16x8*)&R1[(ct * 16 + ln) * 200 + kc * 32 + mq * 8];
        acc[0][ct] = mfma16(afr[0][kc], g, acc[0][ct]);
        acc[1][ct] = mfma16(afr[1][kc], g, acc[1][ct]);
      }
#pragma unroll
    for (int i = 0; i < 2; ++i) {
      const float* wr = W2 + (size_t)(r0 + i * 16 + mq * 4) * C_;
      float nrm[4] = {0.f, 0.f, 0.f, 0.f};
#pragma unroll
      for (int ct = 0; ct < 12; ++ct)
#pragma unroll
        for (int r = 0; r < 4; ++r)
          nrm[r] += acc[i][ct][r] * wr[r * C_ + ct * 16 + ln];
#pragma unroll
      for (int m = 1; m < 16; m <<= 1)
#pragma unroll
        for (int r = 0; r < 4; ++r) nrm[r] += __shfl_xor(nrm[r], m);
      if (ln == 0) {
#pragma unroll
        for (int r = 0; r < 4; ++r) {
          float v = fmaxf(sqrtf(fmaxf(nrm[r], 0.f)), 1e-12f);
          (pass ? qnl : knl)[r0 + i * 16 + mq * 4 + r] = v;
        }
      }
    }
    if (pass == 0) {
#pragma unroll
      for (int i = 0; i < 2; ++i)
#pragma unroll
        for (int ct = 0; ct < 12; ++ct)
#pragma unroll
          for (int r = 0; r < 4; ++r)
            R2[(r0 + i * 16 + mq * 4 + r) * 200 + ct * 16 + ln] = f2bf(acc[i][ct][r]);
    }
  }
  __syncthreads();                                 // Tk/kn/qn ready, R1 reads done
  stage(Wq, R1);
  __syncthreads();

  // ---- phase 2: S = Tk·Wq^T, scale, softmax -> A (regs) ----
  f32x4 acc[2][12];
  {
    u16x8 afr[2][6];
#pragma unroll
    for (int i = 0; i < 2; ++i)
#pragma unroll
      for (int kc = 0; kc < 6; ++kc)
        afr[i][kc] = *(const u16x8*)&R2[(r0 + i * 16 + ln) * 200 + kc * 32 + mq * 8];
#pragma unroll
    for (int i = 0; i < 2; ++i)
#pragma unroll
      for (int j = 0; j < 12; ++j) acc[i][j] = (f32x4)0.0f;
#pragma unroll
    for (int kc = 0; kc < 6; ++kc)
#pragma unroll
      for (int ct = 0; ct < 12; ++ct) {
        u16x8 q = *(const u16x8*)&R1[(ct * 16 + ln) * 200 + kc * 32 + mq * 8];
        acc[0][ct] = mfma16(afr[0][kc], q, acc[0][ct]);
        acc[1][ct] = mfma16(afr[1][kc], q, acc[1][ct]);
      }
  }
  float rqn[12];
#pragma unroll
  for (int ct = 0; ct < 12; ++ct) rqn[ct] = qnl[ct * 16 + ln];
#pragma unroll
  for (int i = 0; i < 2; ++i) {
    float rkn[4];
#pragma unroll
    for (int r = 0; r < 4; ++r) rkn[r] = knl[r0 + i * 16 + mq * 4 + r];
    float mx[4] = {-1e30f, -1e30f, -1e30f, -1e30f};
#pragma unroll
    for (int ct = 0; ct < 12; ++ct)
#pragma unroll
      for (int r = 0; r < 4; ++r) {
        float l = acc[i][ct][r] / (rkn[r] * rqn[ct]);
        acc[i][ct][r] = l;
        mx[r] = fmaxf(mx[r], l);
      }
#pragma unroll
    for (int m = 1; m < 16; m <<= 1)
#pragma unroll
      for (int r = 0; r < 4; ++r) mx[r] = fmaxf(mx[r], __shfl_xor(mx[r], m));
    float sm[4] = {0.f, 0.f, 0.f, 0.f};
#pragma unroll
    for (int ct = 0; ct < 12; ++ct)
#pragma unroll
      for (int r = 0; r < 4; ++r) {
        float e = expf(acc[i][ct][r] - mx[r]);
        acc[i][ct][r] = e;
        sm[r] += e;
      }
#pragma unroll
    for (int m = 1; m < 16; m <<= 1)
#pragma unroll
      for (int r = 0; r < 4; ++r) sm[r] += __shfl_xor(sm[r], m);
    float inv[4];
#pragma unroll
    for (int r = 0; r < 4; ++r) inv[r] = 1.f / sm[r];
#pragma unroll
    for (int ct = 0; ct < 12; ++ct)
#pragma unroll
      for (int r = 0; r < 4; ++r) acc[i][ct][r] *= inv[r];
  }
  __syncthreads();                                 // all reads of R1/R2 complete
  // A -> R2 (bf16); WvT -> R1
#pragma unroll
  for (int i = 0; i < 2; ++i)
#pragma unroll
    for (int ct = 0; ct < 12; ++ct)
#pragma unroll
      for (int r = 0; r < 4; ++r)
        R2[(r0 + i * 16 + mq * 4 + r) * 200 + ct * 16 + ln] = f2bf(acc[i][ct][r]);
  stage(WvT, R1);
  __syncthreads();

  // ---- phase 3: Tv = A·WvT ----
  f32x4 tv[2][12];
  {
    u16x8 afr[2][6];
#pragma unroll
    for (int i = 0; i < 2; ++i)
#pragma unroll
      for (int kc = 0; kc < 6; ++kc)
        afr[i][kc] = *(const u16x8*)&R2[(r0 + i * 16 + ln) * 200 + kc * 32 + mq * 8];
#pragma unroll
    for (int i = 0; i < 2; ++i)
#pragma unroll
      for (int j = 0; j < 12; ++j) tv[i][j] = (f32x4)0.0f;
#pragma unroll
    for (int kc = 0; kc < 6; ++kc)
#pragma unroll
      for (int ct = 0; ct < 12; ++ct) {
        u16x8 q = *(const u16x8*)&R1[(ct * 16 + ln) * 200 + kc * 32 + mq * 8];
        tv[0][ct] = mfma16(afr[0][kc], q, tv[0][ct]);
        tv[1][ct] = mfma16(afr[1][kc], q, tv[1][ct]);
      }
  }
  __syncthreads();                                 // reads of R1 done
  // Tv^T -> R1 (bf16): row = Tv col, col = Tv row
#pragma unroll
  for (int i = 0; i < 2; ++i)
#pragma unroll
    for (int ct = 0; ct < 12; ++ct) {
      uint2 pk;
      pk.x = pkbf(tv[i][ct][0], tv[i][ct][1]);
      pk.y = pkbf(tv[i][ct][2], tv[i][ct][3]);
      *(uint2*)&R1[(ct * 16 + ln) * 200 + r0 + i * 16 + mq * 4] = pk;
    }
  __syncthreads();

  // ---- phase 4: M = Wo2·Tv -> global ----
  {
    u16x8 afr[2][6];
#pragma unroll
    for (int i = 0; i < 2; ++i)
#pragma unroll
      for (int kc = 0; kc < 6; ++kc)
        afr[i][kc] = ld8bf(Wo2 + (size_t)(r0 + i * 16 + ln) * C_ + kc * 32 + mq * 8);
    f32x4 mc[2][12];
#pragma unroll
    for (int i = 0; i < 2; ++i)
#pragma unroll
      for (int j = 0; j < 12; ++j) mc[i][j] = (f32x4)0.0f;
#pragma unroll
    for (int kc = 0; kc < 6; ++kc)
#pragma unroll
      for (int ct = 0; ct < 12; ++ct) {
        u16x8 q = *(const u16x8*)&R1[(ct * 16 + ln) * 200 + kc * 32 + mq * 8];
        mc[0][ct] = mfma16(afr[0][kc], q, mc[0][ct]);
        mc[1][ct] = mfma16(afr[1][kc], q, mc[1][ct]);
      }
#pragma unroll
    for (int i = 0; i < 2; ++i)
#pragma unroll
      for (int ct = 0; ct < 12; ++ct)
#pragma unroll
        for (int r = 0; r < 4; ++r)
          Mw[(size_t)b * CC2 + (r0 + i * 16 + mq * 4 + r) * C_ + ct * 16 + ln] =
              mc[i][ct][r];
  }
}

// ---------------- final: out[b] = M[b] @ X[b] + bias2, bf16 MFMA ----------------
// v3b (measured 59.4 us): 64-px blocks, 24 KB LDS, 2-section register-prefetch,
// packed b64 LDS writes, swizzle key (p>>1)&7, __launch_bounds__(384,4) (no spill).
__global__ __launch_bounds__(384, 4) void final3_kernel(const float* __restrict__ xin,
                                                        const float* __restrict__ Mw,
                                                        const float* __restrict__ bias2,
                                                        float* __restrict__ out) {
  const int b = blockIdx.y;
  const int p0 = blockIdx.x * 64;
  __shared__ __align__(16) unsigned short Ts[64 * 192];   // 24 KB swizzled [p][c]
  const int tid = threadIdx.x;
  const int wv = tid >> 6;                         // 0..5, wave owns rows 32*wv..+31
  const int lane = tid & 63;
  const int ln = lane & 15, mq = lane >> 4;
  const float* Mb = Mw + (size_t)b * CC2;

  // staging map: c-quad c0 = (tid>>3)*4 (48 quads), px-quad pq = tid&7 (8 per section)
  const int c0 = (tid >> 3) * 4;
  const int pq = tid & 7;
  const float* xsrc = xin + ((size_t)b * C_ + c0) * N_ + p0 + pq * 4;

  float4 ldA[4], ldB[4];
#pragma unroll
  for (int l = 0; l < 4; ++l) ldA[l] = *(const float4*)(xsrc + (size_t)l * N_);

  // M fragments (bf16) + bias, loaded once per block
  u16x8 afr[6][2];
  float bo[2][4];
#pragma unroll
  for (int i = 0; i < 2; ++i) {
    int row = 32 * wv + 16 * i + ln;
#pragma unroll
    for (int kc = 0; kc < 6; ++kc)
      afr[kc][i] = ld8bf(Mb + row * C_ + kc * 32 + mq * 8);
#pragma unroll
    for (int r = 0; r < 4; ++r) bo[i][r] = bias2[32 * wv + 16 * i + mq * 4 + r];
  }

  auto stage_write = [&](const float4* ld, int sbase) {
#pragma unroll
    for (int e = 0; e < 4; ++e) {                  // e compile-time: direct .x/.y/.z/.w
      int p = sbase + pq * 4 + e;
      int idx = p * 192 + ((((c0 >> 3) ^ ((p >> 1) & 7)) << 3) | (c0 & 7));
      uint2 pk;
      pk.x = pkbf(f4get(ld[0], e), f4get(ld[1], e));
      pk.y = pkbf(f4get(ld[2], e), f4get(ld[3], e));
      *(uint2*)&Ts[idx] = pk;                      // ds_write_b64
    }
  };

  auto compute = [&](int pt) {
    const int p = pt * 16 + ln;
    const int pkey = (p >> 1) & 7;
    f32x4 acc0 = (f32x4)0.0f, acc1 = (f32x4)0.0f;
#pragma unroll
    for (int kc = 0; kc < 6; ++kc) {
      u16x8 bf = *(const u16x8*)&Ts[p * 192 + (((kc * 4 + mq) ^ pkey) << 3)];
      acc0 = mfma16(afr[kc][0], bf, acc0);
      acc1 = mfma16(afr[kc][1], bf, acc1);
    }
    const int pp = p0 + p;
#pragma unroll
    for (int r = 0; r < 4; ++r) {
      int row0 = 32 * wv + mq * 4 + r;
      out[((size_t)b * C_ + row0) * N_ + pp] = acc0[r] + bo[0][r];
      out[((size_t)b * C_ + row0 + 16) * N_ + pp] = acc1[r] + bo[1][r];
    }
  };

  stage_write(ldA, 0);
  __syncthreads();
#pragma unroll
  for (int l = 0; l < 4; ++l) ldB[l] = *(const float4*)(xsrc + 32 + (size_t)l * N_);
  compute(0);
  compute(1);
  stage_write(ldB, 32);                            // waits vmcnt here, after MFMA
  __syncthreads();
  compute(2);
  compute(3);
}

extern "C" void kernel_launch(void* const* d_in, const int* in_sizes, int n_in,
                              void* d_out, int out_size, void* d_ws, size_t ws_size,
                              hipStream_t stream) {
  const float* xin    = (const float*)d_in[0];
  const float* wsplit = (const float*)d_in[1];
  const float* wq     = (const float*)d_in[2];
  const float* wk     = (const float*)d_in[3];
  const float* wv     = (const float*)d_in[4];
  const float* wproj  = (const float*)d_in[5];
  const float* bproj  = (const float*)d_in[6];
  const float* wout   = (const float*)d_in[7];
  float* out = (float*)d_out;

  float* ws = (float*)d_ws;
  float* G     = ws;                         // B*CC2
  float* Wq    = G + (size_t)B_ * CC2;       // CC2
  float* WvT   = Wq + CC2;
  float* Wk    = WvT + CC2;
  float* Wv    = Wk + CC2;
  float* Wo2   = Wv + CC2;
  float* bias2 = Wo2 + CC2;                  // 256
  float* Mw    = bias2 + 256;                // B*CC2
  float* P     = Mw + (size_t)B_ * CC2;      // B*NCHUNK*CC2 (37.7 MB) if it fits

  size_t base_floats = (size_t)(P - ws);
  size_t need_bytes = (base_floats + (size_t)B_ * NCHUNK * CC2) * sizeof(float);
  bool use_partials = ws_size >= need_bytes;

  fold_kernel<<<(4 * CC2 + 255) / 256, 256, 0, stream>>>(
      wsplit, wq, wk, wv, wproj, bproj, wout, Wq, WvT, Wk, Wv, Wo2, bias2);
  if (use_partials) {
    gram3_kernel<false><<<dim3(NCHUNK, 2, B_), 384, 0, stream>>>(xin, P);
    gsum_kernel<<<dim3(CC2 / 1024, B_), 256, 0, stream>>>(P, G);
  } else {
    hipMemsetAsync(G, 0, (size_t)B_ * CC2 * sizeof(float), stream);
    gram3_kernel<true><<<dim3(NCHUNK, 2, B_), 384, 0, stream>>>(xin, G);
  }
  middle8_kernel<<<dim3(B_), 384, 0, stream>>>(G, Wk, Wq, WvT, Wo2, Mw);
  final3_kernel<<<dim3(N_ / 64, B_), 384, 0, stream>>>(xin, Mw, bias2, out);
}